// Round 2
// baseline (31.912 us; speedup 1.0000x reference)
//
#include <hip/hip_runtime.h>
#include <hip/hip_bf16.h>

// Shapes: x,gn (8,128,64) f32; fb (1,128,32768) f32; resonance (64,128) f32.
// out (8,1,32768) f32.
// r[b,c,f] = sum_rr softmax(x+gn)[b,c,rr] * res[rr,f]
// out[b,s] = (1/128) * sum_c lerp(r[b,c,:], s) * fb[c,s]
//          = (1/128) * [ (1-w)*dot(fb[:,s], rlo[b,:]) + w*dot(fb[:,s], rhi[b,:]) ]

#define BATCH 8
#define BANDS 128
#define RES 64
#define NF 128
#define NS 32768

// ---------------- Kernel A: softmax + matvec -> rT[f][b*128+c] ----------------
__global__ __launch_bounds__(64) void kA(const float* __restrict__ x,
                                         const float* __restrict__ gn,
                                         const float* __restrict__ res,
                                         float* __restrict__ rT) {
    const int bc = blockIdx.x;        // b*128 + c, 0..1023
    const int t  = threadIdx.x;       // 0..63 (one full wave)

    float v = x[bc * RES + t] + gn[bc * RES + t];

    // wave-wide max + sum (64 lanes)
    float m = v;
    #pragma unroll
    for (int off = 32; off > 0; off >>= 1)
        m = fmaxf(m, __shfl_xor(m, off));
    float e = expf(v - m);
    float ssum = e;
    #pragma unroll
    for (int off = 32; off > 0; off >>= 1)
        ssum += __shfl_xor(ssum, off);
    float g = e / ssum;

    __shared__ float gs[RES];
    gs[t] = g;
    __syncthreads();

    // each thread computes frames f=t and f=t+64
    float r0 = 0.f, r1 = 0.f;
    #pragma unroll 4
    for (int rr = 0; rr < RES; ++rr) {
        float gg = gs[rr];
        r0 = fmaf(gg, res[rr * NF + t], r0);
        r1 = fmaf(gg, res[rr * NF + t + 64], r1);
    }
    rT[t * (BATCH * BANDS) + bc]        = r0;
    rT[(t + 64) * (BATCH * BANDS) + bc] = r1;
}

// ---------------- Kernel B: two dot-products + lerp of the dots ----------------
// Block = (segment of 256 samples) x (one batch). lo is wave-uniform:
// integer crossings of pos(s) occur at s == 127.5 (mod 256), never inside a
// 64-aligned 64-sample run, so all 64 lanes of a wave share lo ->
// readfirstlane makes the r-rows SGPR-resident (s_load), no LDS needed.
__global__ __launch_bounds__(256) void kB(const float* __restrict__ fb,
                                          const float* __restrict__ rT,
                                          float* __restrict__ out) {
    const int blk = blockIdx.x;       // 0..1023
    const int b   = blk & (BATCH - 1);
    const int seg = blk >> 3;         // 0..127
    const int tid = threadIdx.x;      // 0..255
    const int s   = seg * 256 + tid;

    float pos = (s + 0.5f) * (1.0f / 256.0f) - 0.5f;
    pos = fminf(fmaxf(pos, 0.0f), (float)(NF - 1));
    int lo = (int)floorf(pos);
    const float w = pos - (float)lo;
    lo = __builtin_amdgcn_readfirstlane(lo);   // wave-uniform by construction
    const int hi = min(lo + 1, NF - 1);

    const float* __restrict__ rlo = rT + lo * (BATCH * BANDS) + b * BANDS;
    const float* __restrict__ rhi = rT + hi * (BATCH * BANDS) + b * BANDS;

    float pl = 0.f, ph = 0.f;
    #pragma unroll 16
    for (int c = 0; c < BANDS; ++c) {
        const float f = fb[c * NS + s];   // coalesced, 256B/wave
        pl = fmaf(f, rlo[c], pl);         // SGPR operand
        ph = fmaf(f, rhi[c], ph);         // SGPR operand
    }
    out[b * NS + s] = fmaf(w, ph - pl, pl) * (1.0f / (float)BANDS);
}

extern "C" void kernel_launch(void* const* d_in, const int* in_sizes, int n_in,
                              void* d_out, int out_size, void* d_ws, size_t ws_size,
                              hipStream_t stream) {
    const float* x   = (const float*)d_in[0];
    const float* gn  = (const float*)d_in[1];
    const float* fb  = (const float*)d_in[2];
    const float* res = (const float*)d_in[3];
    float* out = (float*)d_out;
    float* rT  = (float*)d_ws;   // NF * BATCH * BANDS floats = 512 KB

    kA<<<BATCH * BANDS, 64, 0, stream>>>(x, gn, res, rT);
    kB<<<(NS / 256) * BATCH, 256, 0, stream>>>(fb, rT, out);
}

// Round 3
// 18.201 us; speedup vs baseline: 1.7533x; 1.7533x over previous
//
#include <hip/hip_runtime.h>
#include <hip/hip_bf16.h>

// Shapes: x,gn (8,128,64) f32; fb (1,128,32768) f32; resonance (64,128) f32.
// out (8,1,32768) f32.
// r[b,c,f] = sum_rr softmax(x+gn)[b,c,rr] * res[rr,f]
// out[b,s] = (1/128) * sum_c lerp(r[b,c,:], s) * fb[c,s]

#define BATCH 8
#define BANDS 128
#define RES 64
#define NF 128
#define NS 32768

// ---------------- Kernel A: softmax + matvec -> rT[f][b*128+c] ----------------
__global__ __launch_bounds__(64) void kA(const float* __restrict__ x,
                                         const float* __restrict__ gn,
                                         const float* __restrict__ res,
                                         float* __restrict__ rT) {
    const int bc = blockIdx.x;        // b*128 + c, 0..1023
    const int t  = threadIdx.x;       // 0..63 (one full wave)

    float v = x[bc * RES + t] + gn[bc * RES + t];

    // wave-wide max + sum (64 lanes)
    float m = v;
    #pragma unroll
    for (int off = 32; off > 0; off >>= 1)
        m = fmaxf(m, __shfl_xor(m, off));
    float e = expf(v - m);
    float ssum = e;
    #pragma unroll
    for (int off = 32; off > 0; off >>= 1)
        ssum += __shfl_xor(ssum, off);
    float g = e / ssum;

    __shared__ float gs[RES];
    gs[t] = g;
    __syncthreads();

    // each thread computes frames f=t and f=t+64
    float r0 = 0.f, r1 = 0.f;
    #pragma unroll 4
    for (int rr = 0; rr < RES; ++rr) {
        float gg = gs[rr];
        r0 = fmaf(gg, res[rr * NF + t], r0);
        r1 = fmaf(gg, res[rr * NF + t + 64], r1);
    }
    rT[t * (BATCH * BANDS) + bc]        = r0;
    rT[(t + 64) * (BATCH * BANDS) + bc] = r1;
}

// ---------------- Kernel B: interp + fb multiply + band mean ----------------
// Block k handles 64 samples [64k, 64k+63], all 8 batches (4 waves x 2 batches).
// For a 64-sample segment, frac(pos0) <= 0.752 and pos span < 0.25, so
// floor(pos) is BLOCK-uniform -> stage exactly 2 frames as rlo + dd in LDS.
// fb is read once per block (coalesced); waves 1-3 hit L1 (32 KB tile).
// LDS reads are wave-uniform broadcasts -> zero bank conflicts.
__global__ __launch_bounds__(256) void kB(const float* __restrict__ fb,
                                          const float* __restrict__ rT,
                                          float* __restrict__ out) {
    const int k   = blockIdx.x;       // 0..511
    const int tid = threadIdx.x;      // 0..255
    const int bg  = tid >> 6;         // wave id = batch-group 0..3
    const int t   = tid & 63;         // sample within segment
    const int s   = k * 64 + t;

    __shared__ float rlo_s[BATCH * BANDS];
    __shared__ float dd_s[BATCH * BANDS];

    // block-uniform lo
    float pos0 = ((float)(k * 64) + 0.5f) * (1.0f / 256.0f) - 0.5f;
    pos0 = fminf(fmaxf(pos0, 0.0f), (float)(NF - 1));
    const int lo0 = (int)floorf(pos0);
    const int f1  = min(lo0 + 1, NF - 1);

    for (int i = tid; i < BATCH * BANDS; i += 256) {
        const float a = rT[lo0 * (BATCH * BANDS) + i];
        const float b = rT[f1  * (BATCH * BANDS) + i];
        rlo_s[i] = a;
        dd_s[i]  = b - a;
    }
    __syncthreads();

    float pos = ((float)s + 0.5f) * (1.0f / 256.0f) - 0.5f;
    pos = fminf(fmaxf(pos, 0.0f), (float)(NF - 1));
    const float w = pos - (float)lo0;   // lo is block-uniform by construction

    const int b0 = bg * 2;
    const float* __restrict__ rl0 = &rlo_s[(b0 + 0) * BANDS];
    const float* __restrict__ rl1 = &rlo_s[(b0 + 1) * BANDS];
    const float* __restrict__ dp0 = &dd_s[(b0 + 0) * BANDS];
    const float* __restrict__ dp1 = &dd_s[(b0 + 1) * BANDS];

    float acc0 = 0.f, acc1 = 0.f;
    #pragma unroll 8
    for (int c = 0; c < BANDS; c += 4) {
        const float f0 = fb[(c + 0) * NS + s];
        const float f1v = fb[(c + 1) * NS + s];
        const float f2 = fb[(c + 2) * NS + s];
        const float f3 = fb[(c + 3) * NS + s];

        const float4 r0 = *(const float4*)&rl0[c];
        const float4 d0 = *(const float4*)&dp0[c];
        acc0 = fmaf(f0,  fmaf(w, d0.x, r0.x), acc0);
        acc0 = fmaf(f1v, fmaf(w, d0.y, r0.y), acc0);
        acc0 = fmaf(f2,  fmaf(w, d0.z, r0.z), acc0);
        acc0 = fmaf(f3,  fmaf(w, d0.w, r0.w), acc0);

        const float4 r1 = *(const float4*)&rl1[c];
        const float4 d1 = *(const float4*)&dp1[c];
        acc1 = fmaf(f0,  fmaf(w, d1.x, r1.x), acc1);
        acc1 = fmaf(f1v, fmaf(w, d1.y, r1.y), acc1);
        acc1 = fmaf(f2,  fmaf(w, d1.z, r1.z), acc1);
        acc1 = fmaf(f3,  fmaf(w, d1.w, r1.w), acc1);
    }

    out[(b0 + 0) * NS + s] = acc0 * (1.0f / (float)BANDS);
    out[(b0 + 1) * NS + s] = acc1 * (1.0f / (float)BANDS);
}

extern "C" void kernel_launch(void* const* d_in, const int* in_sizes, int n_in,
                              void* d_out, int out_size, void* d_ws, size_t ws_size,
                              hipStream_t stream) {
    const float* x   = (const float*)d_in[0];
    const float* gn  = (const float*)d_in[1];
    const float* fb  = (const float*)d_in[2];
    const float* res = (const float*)d_in[3];
    float* out = (float*)d_out;
    float* rT  = (float*)d_ws;   // NF * BATCH * BANDS floats = 512 KB

    kA<<<BATCH * BANDS, 64, 0, stream>>>(x, gn, res, rT);
    kB<<<NS / 64, 256, 0, stream>>>(fb, rT, out);
}